// Round 10
// baseline (715.927 us; speedup 1.0000x reference)
//
#include <hip/hip_runtime.h>

#define BN_EPS 1e-5f

typedef __attribute__((ext_vector_type(8))) short bf16x8;
typedef __attribute__((ext_vector_type(4))) float f32x4;

union VU {
    uint4 u;
    bf16x8 b;
};

// ---------------- CSR build: LDS multi-split bucket sort ----------------
// Bucket b = dst >> 10 (1024 nodes/bucket, NB = ceil(N/1024) <= 128).
// bin_k: per-block LDS histogram assigns local ranks (LDS atomics), ONE global
// atomic per (block,bucket) reserves a run -> 77K global atomics on line-padded
// counters instead of 1.6M on 49 shared lines (the round-1 510us serialization).

__global__ __launch_bounds__(256) void hist_k(const int* __restrict__ dst, int E,
                                              int* __restrict__ ghist, int NB) {
    __shared__ int lh[128];
    if (threadIdx.x < 128) lh[threadIdx.x] = 0;
    __syncthreads();
    for (int i = blockIdx.x * 256 + threadIdx.x; i < E; i += gridDim.x * 256)
        atomicAdd(&lh[dst[i] >> 10], 1);
    __syncthreads();
    if (threadIdx.x < 128 && threadIdx.x < NB && lh[threadIdx.x])
        atomicAdd(&ghist[threadIdx.x * 16], lh[threadIdx.x]);
}

// One-block scan over NB bucket counts (NB <= 128).
__global__ __launch_bounds__(128) void pscan_k(const int* __restrict__ ghist, int NB,
                                               int* __restrict__ sbase, int* __restrict__ csrB,
                                               int* __restrict__ rowptr, int n, int E) {
    __shared__ int pa[128], pc[128];
    int t = threadIdx.x;
    int v = (t < NB) ? ghist[t * 16] : 0;
    int vp = (v + 15) & ~15;
    pa[t] = vp;
    pc[t] = v;
    __syncthreads();
    for (int s = 1; s < 128; s <<= 1) {
        int ta = (t >= s) ? pa[t - s] : 0;
        int tc = (t >= s) ? pc[t - s] : 0;
        __syncthreads();
        pa[t] += ta;
        pc[t] += tc;
        __syncthreads();
    }
    if (t < NB) {
        sbase[t] = pa[t] - vp;
        csrB[t] = pc[t] - v;
        if (t == NB - 1) {
            csrB[NB] = pc[t];
            rowptr[n] = E;
        }
    }
}

// LDS multi-split: 2048-edge chunk per block; local ranks via LDS atomics,
// one global atomic per bucket per block, then scatter packed (src | dstLocal<<17).
#define CHUNK 2048
__global__ __launch_bounds__(256) void bin_k(const int* __restrict__ src, const int* __restrict__ dst, int E,
                                             const int* __restrict__ sbase, int* __restrict__ snext,
                                             int* __restrict__ staged, int NB) {
    __shared__ int hist[128];
    __shared__ int base[128];
    int t = threadIdx.x;
    int c0 = blockIdx.x * CHUNK;
    if (c0 >= E) return;
    if (t < 128) hist[t] = 0;
    __syncthreads();
    int bk[8], pk[8], rk[8];
#pragma unroll
    for (int k = 0; k < 8; ++k) {
        int i = c0 + k * 256 + t;
        bk[k] = -1;
        if (i < E) {
            int d = dst[i];
            int b = d >> 10;
            bk[k] = b;
            pk[k] = src[i] | ((d & 1023) << 17);
            rk[k] = atomicAdd(&hist[b], 1);
        }
    }
    __syncthreads();
    if (t < NB) base[t] = sbase[t] + atomicAdd(&snext[t * 16], hist[t]);
    __syncthreads();
#pragma unroll
    for (int k = 0; k < 8; ++k)
        if (bk[k] >= 0) staged[base[bk[k]] + rk[k]] = pk[k];
}

// One block per bucket: LDS count + scan over 1024 local nodes, write rowptr,
// then scatter ssrc within the bucket's contiguous (~64KB) CSR region.
__global__ __launch_bounds__(1024) void csr_k(const int* __restrict__ staged, const int* __restrict__ ghist,
                                              const int* __restrict__ sbase, const int* __restrict__ csrB,
                                              int* __restrict__ rowptr, int* __restrict__ ssrc, int n) {
    __shared__ int hist[1024], cur[1024];
    int b = blockIdx.x, t = threadIdx.x;
    int nodeBase = b << 10;
    hist[t] = 0;
    __syncthreads();
    int s0 = sbase[b], c = ghist[b * 16];
    for (int j = t; j < c; j += 1024) atomicAdd(&hist[staged[s0 + j] >> 17], 1);
    __syncthreads();
    int v = hist[t];
    for (int s = 1; s < 1024; s <<= 1) {
        int tv = (t >= s) ? hist[t - s] : 0;
        __syncthreads();
        hist[t] += tv;
        __syncthreads();
    }
    int ex = hist[t] - v;
    int cb = csrB[b];
    if (nodeBase + t < n) rowptr[nodeBase + t] = cb + ex;
    cur[t] = ex;
    __syncthreads();
    for (int j = t; j < c; j += 1024) {
        int e = staged[s0 + j];
        int p = atomicAdd(&cur[e >> 17], 1);
        ssrc[cb + p] = e & 131071;
    }
}

// ---------------- helpers ----------------

static __device__ __forceinline__ unsigned short f2bf(float f) {
    unsigned u = __float_as_uint(f);
    unsigned r = (u + 0x7FFFu + ((u >> 16) & 1u)) >> 16;  // RNE
    return (unsigned short)r;
}
static __device__ __forceinline__ float bf_lo(unsigned u) { return __uint_as_float(u << 16); }
static __device__ __forceinline__ float bf_hi(unsigned u) { return __uint_as_float(u & 0xFFFF0000u); }

// ---------------- prep: pack W into bf16 MFMA fragments + fold zero-inits ----------------
// Also zeroes the H pad row (slice stride n+16, row n of each slice): masked
// aggregation slots gather this zero row -> no sc-predicate in the hot loop.

__global__ __launch_bounds__(256) void prepw_k(const float* __restrict__ Ws, uint4* __restrict__ Wp,
                                               int* __restrict__ ghist, int* __restrict__ snext,
                                               float* __restrict__ stats, int* __restrict__ ssrcPad,
                                               unsigned short* __restrict__ h, int NB16, int n, int np) {
    int id = blockIdx.x * 256 + threadIdx.x;
    // folded zero-inits (replaces hipMemsetAsync launches)
    if (id < NB16) ghist[id] = 0;
    else if (id < 2 * NB16) snext[id - NB16] = 0;
    else if (id < 2 * NB16 + 512) stats[id - 2 * NB16] = 0.f;
    else if (id < 2 * NB16 + 512 + 256) ssrcPad[id - 2 * NB16 - 512] = 0;
    if (id >= 4096 && id < 4096 + 128) {
        int sl = (id - 4096) >> 4, ft = (id - 4096) & 15;
        h[((size_t)sl * np + n) * 16 + ft] = 0;  // zero pad row of each slice
    }
    if (id >= 3 * 4 * 8 * 64) return;
    int lane = id & 63;
    int nt = (id >> 6) & 7;
    int kt = (id >> 9) & 3;
    int L = id >> 11;
    int quad = lane >> 4, l16 = lane & 15;
    const float* wsrc = Ws + L * 16384 + (kt * 32 + quad * 8) * 128 + nt * 16 + l16;
    unsigned short s[8];
#pragma unroll
    for (int j = 0; j < 8; ++j) s[j] = f2bf(wsrc[j * 128]);
    uint4 pk;
    pk.x = (unsigned)s[0] | ((unsigned)s[1] << 16);
    pk.y = (unsigned)s[2] | ((unsigned)s[3] << 16);
    pk.z = (unsigned)s[4] | ((unsigned)s[5] << 16);
    pk.w = (unsigned)s[6] | ((unsigned)s[7] << 16);
    Wp[id] = pk;
}

// ---------------- MFMA GEMM: H(bf16, SLICE-MAJOR, stride np=n+16) = f(X) @ Wp ----------------
// Slice-major: slice s at H + s*np*16, rows 0..n-1 computed, row n = zero pad.
// MODE 0: X = f32 row-major (cvt fused).  MODE 1: X = bf16 slice-major, f = BN+ReLU (fused).

template <int MODE>
__global__ __launch_bounds__(256) void mgemm_k(const float* __restrict__ Xf, const unsigned short* __restrict__ Xb,
                                               const uint4* __restrict__ Wp, unsigned short* __restrict__ H,
                                               const float* __restrict__ ss, int n, int np) {
    int lane = threadIdx.x & 63;
    int quad = lane >> 4, l16 = lane & 15;
    int wid = (blockIdx.x * 256 + threadIdx.x) >> 6;
    int nw = (gridDim.x * 256) >> 6;
    int ntiles = (n + 15) >> 4;

    VU b[4][8];
#pragma unroll
    for (int kt = 0; kt < 4; ++kt)
#pragma unroll
        for (int nt = 0; nt < 8; ++nt) b[kt][nt].u = Wp[(kt * 8 + nt) * 64 + lane];

    auto loadA = [&](int tile, VU* a) {
        int row = tile * 16 + l16;
#pragma unroll
        for (int kt = 0; kt < 4; ++kt) {
            float f[8];
            if (MODE == 0) {
                const float* xr = Xf + (size_t)row * 128 + kt * 32 + quad * 8;
                float4 u0 = *(const float4*)(xr);
                float4 u1 = *(const float4*)(xr + 4);
                f[0] = u0.x; f[1] = u0.y; f[2] = u0.z; f[3] = u0.w;
                f[4] = u1.x; f[5] = u1.y; f[6] = u1.z; f[7] = u1.w;
            } else {
                int sl = kt * 2 + (quad >> 1);
                uint4 u = *(const uint4*)(Xb + ((size_t)sl * np + row) * 16 + (quad & 1) * 8);
                f[0] = bf_lo(u.x); f[1] = bf_hi(u.x); f[2] = bf_lo(u.y); f[3] = bf_hi(u.y);
                f[4] = bf_lo(u.z); f[5] = bf_hi(u.z); f[6] = bf_lo(u.w); f[7] = bf_hi(u.w);
                const float4* scp = (const float4*)(ss + kt * 32 + quad * 8);
                const float4* shp = (const float4*)(ss + 128 + kt * 32 + quad * 8);
                float4 c0 = scp[0], c1 = scp[1], d0 = shp[0], d1 = shp[1];
                f[0] = fmaxf(fmaf(f[0], c0.x, d0.x), 0.f);
                f[1] = fmaxf(fmaf(f[1], c0.y, d0.y), 0.f);
                f[2] = fmaxf(fmaf(f[2], c0.z, d0.z), 0.f);
                f[3] = fmaxf(fmaf(f[3], c0.w, d0.w), 0.f);
                f[4] = fmaxf(fmaf(f[4], c1.x, d1.x), 0.f);
                f[5] = fmaxf(fmaf(f[5], c1.y, d1.y), 0.f);
                f[6] = fmaxf(fmaf(f[6], c1.z, d1.z), 0.f);
                f[7] = fmaxf(fmaf(f[7], c1.w, d1.w), 0.f);
            }
            uint4 pk;
            pk.x = (unsigned)f2bf(f[0]) | ((unsigned)f2bf(f[1]) << 16);
            pk.y = (unsigned)f2bf(f[2]) | ((unsigned)f2bf(f[3]) << 16);
            pk.z = (unsigned)f2bf(f[4]) | ((unsigned)f2bf(f[5]) << 16);
            pk.w = (unsigned)f2bf(f[6]) | ((unsigned)f2bf(f[7]) << 16);
            a[kt].u = pk;
        }
    };

    int t = wid;
    VU a[4];
    if (t < ntiles) loadA(t, a);

    while (t < ntiles) {
        int tn = t + nw;
        VU an[4];
        if (tn < ntiles) loadA(tn, an);

        f32x4 acc[8];
#pragma unroll
        for (int nt = 0; nt < 8; ++nt) acc[nt] = (f32x4){0.f, 0.f, 0.f, 0.f};
#pragma unroll
        for (int kt = 0; kt < 4; ++kt)
#pragma unroll
            for (int nt = 0; nt < 8; ++nt)
                acc[nt] = __builtin_amdgcn_mfma_f32_16x16x32_bf16(b[kt][nt].b, a[kt].b, acc[nt], 0, 0, 0);

        int row = t * 16 + l16;
#pragma unroll
        for (int nt = 0; nt < 8; ++nt) {
            uint2 pk;
            pk.x = (unsigned)f2bf(acc[nt][0]) | ((unsigned)f2bf(acc[nt][1]) << 16);
            pk.y = (unsigned)f2bf(acc[nt][2]) | ((unsigned)f2bf(acc[nt][3]) << 16);
            *(uint2*)(H + ((size_t)nt * np + row) * 16 + quad * 4) = pk;
        }

#pragma unroll
        for (int kt = 0; kt < 4; ++kt) a[kt] = an[kt];
        t = tn;
    }
}

// ---------------- Sliced aggregation, 8 nodes per wave (round-8 structure) ----------------
// slice = blockIdx & 7 (XCD-pinned, L2-resident 3.2 MB slice). SEQUENTIAL node
// order. Counted loop (wave-max degree) + zero-pad-row unconditional adds.
// NEW: all STREAMING accesses (rowptr, ssrc, output stores) are non-temporal so
// they don't evict the L2-resident H slice -- FETCH showed H re-fetched ~3x
// (80MB vs 25.6MB) because write-allocate + ssrc stream thrashed L2.

template <int MODE>
__global__ __launch_bounds__(256) void aggs_k(const unsigned short* __restrict__ H, const int* __restrict__ rowptr,
                                              const int* __restrict__ ssrc, unsigned* __restrict__ outb,
                                              float* __restrict__ outf, float* __restrict__ stats, int n, int np) {
    __shared__ float sred[4][4][8];
    int slice = blockIdx.x & 7;
    int bg = blockIdx.x >> 3;
    int lane = threadIdx.x & 63;
    int wv = threadIdx.x >> 6;
    int g = lane >> 3;  // node group
    int f = lane & 7;   // feature pair: feats 2f, 2f+1 of this slice
    int wid = bg * 4 + wv;
    int nwave = (gridDim.x >> 3) * 4;
    const unsigned short* hs = H + (size_t)slice * np * 16 + f * 2;
    float s0 = 0, s1 = 0, q0 = 0, q1 = 0;

    for (int base = wid * 8; base < n; base += nwave * 8) {
        int node = base + g;
        bool valid = node < n;
        int cn = valid ? node : (n - 1);
        int beg = __builtin_nontemporal_load(rowptr + cn);
        int end = valid ? __builtin_nontemporal_load(rowptr + cn + 1) : beg;
        float ax = 0.f, ay = 0.f;

        int md = end - beg;
        md = max(md, __shfl_xor(md, 8));
        md = max(md, __shfl_xor(md, 16));
        md = max(md, __shfl_xor(md, 32));
        int nb = (md + 7) >> 3;

        int idx[8];
#pragma unroll
        for (int k = 0; k < 8; ++k) {
            int j = beg + k;
            idx[k] = (j < end) ? __builtin_nontemporal_load(ssrc + j) : n;  // pad row (zeros)
        }

        int j0 = beg;
        for (int it = 0; it < nb; ++it) {
            unsigned v[8];
#pragma unroll
            for (int k = 0; k < 8; ++k) v[k] = *(const unsigned*)(hs + (size_t)(unsigned)idx[k] * 16);
            int idn[8];
#pragma unroll
            for (int k = 0; k < 8; ++k) {
                int j = j0 + 8 + k;
                idn[k] = (j < end) ? __builtin_nontemporal_load(ssrc + j) : n;  // prefetch next batch
            }
#pragma unroll
            for (int k = 0; k < 8; ++k) {
                ax += bf_lo(v[k]);
                ay += bf_hi(v[k]);
            }
#pragma unroll
            for (int k = 0; k < 8; ++k) idx[k] = idn[k];
            j0 += 8;
        }

        if (MODE == 0) {
            if (valid) {
                unsigned pk = (unsigned)f2bf(ax) | ((unsigned)f2bf(ay) << 16);
                __builtin_nontemporal_store(pk, outb + ((size_t)slice * np + node) * 8 + f);
            }
            s0 += ax; q0 += ax * ax;
            s1 += ay; q1 += ay * ay;
        } else {
            if (valid) {
                float2 pv = make_float2(ax, ay);
                __builtin_nontemporal_store(*(const double*)&pv,
                                            (double*)(outf + (size_t)node * 128 + slice * 16 + f * 2));
            }
        }
    }

    if (MODE == 0) {
        // combine the 8 node-groups (lane bits 3,4,5), then cross-wave via LDS
        s0 += __shfl_xor(s0, 8); s0 += __shfl_xor(s0, 16); s0 += __shfl_xor(s0, 32);
        s1 += __shfl_xor(s1, 8); s1 += __shfl_xor(s1, 16); s1 += __shfl_xor(s1, 32);
        q0 += __shfl_xor(q0, 8); q0 += __shfl_xor(q0, 16); q0 += __shfl_xor(q0, 32);
        q1 += __shfl_xor(q1, 8); q1 += __shfl_xor(q1, 16); q1 += __shfl_xor(q1, 32);
        if (g == 0) {
            sred[wv][0][f] = s0;
            sred[wv][1][f] = s1;
            sred[wv][2][f] = q0;
            sred[wv][3][f] = q1;
        }
        __syncthreads();
        if (wv == 0 && g == 0) {
            float t0 = (sred[0][0][f] + sred[1][0][f]) + (sred[2][0][f] + sred[3][0][f]);
            float t1 = (sred[0][1][f] + sred[1][1][f]) + (sred[2][1][f] + sred[3][1][f]);
            float t2 = (sred[0][2][f] + sred[1][2][f]) + (sred[2][2][f] + sred[3][2][f]);
            float t3 = (sred[0][3][f] + sred[1][3][f]) + (sred[2][3][f] + sred[3][3][f]);
            atomicAdd(&stats[slice * 16 + 2 * f], t0);
            atomicAdd(&stats[slice * 16 + 2 * f + 1], t1);
            atomicAdd(&stats[128 + slice * 16 + 2 * f], t2);
            atomicAdd(&stats[128 + slice * 16 + 2 * f + 1], t3);
        }
    }
}

// ---------------- log_softmax in-place over out [n][128] ----------------

__global__ __launch_bounds__(256) void lsm_k(float* __restrict__ out, int n) {
    int lane = threadIdx.x & 63;
    int wid = (blockIdx.x * 256 + threadIdx.x) >> 6;
    int nw = (gridDim.x * 256) >> 6;
    for (int node = wid; node < n; node += nw) {
        float2 v = *(float2*)(out + (size_t)node * 128 + 2 * lane);
        float m = fmaxf(v.x, v.y);
#pragma unroll
        for (int off = 32; off > 0; off >>= 1) m = fmaxf(m, __shfl_xor(m, off));
        float ex = expf(v.x - m) + expf(v.y - m);
#pragma unroll
        for (int off = 32; off > 0; off >>= 1) ex += __shfl_xor(ex, off);
        float lse = m + logf(ex);
        *(float2*)(out + (size_t)node * 128 + 2 * lane) = make_float2(v.x - lse, v.y - lse);
    }
}

// ---------------- BN finalize ----------------

__global__ void bnfin_k(const float* __restrict__ stats, const float* __restrict__ gamma,
                        const float* __restrict__ beta, float* __restrict__ ss, int n) {
    int f = threadIdx.x;
    if (f < 128) {
        float mu = stats[f] / n;
        float var = stats[128 + f] / n - mu * mu;
        float rs = rsqrtf(fmaxf(var, 0.f) + BN_EPS);
        float sc = gamma[f] * rs;
        ss[f] = sc;
        ss[128 + f] = beta[f] - mu * sc;
    }
}

// ---------------- driver ----------------

extern "C" void kernel_launch(void* const* d_in, const int* in_sizes, int n_in,
                              void* d_out, int out_size, void* d_ws, size_t ws_size,
                              hipStream_t stream) {
    const float* x = (const float*)d_in[0];
    const int* ei = (const int*)d_in[1];
    const float* Ws = (const float*)d_in[2];
    const float* gammas = (const float*)d_in[3];
    const float* betas = (const float*)d_in[4];
    int N = in_sizes[0] / 128;
    int E = in_sizes[1] / 2;
    const int* src = ei;
    const int* dst = ei + E;
    float* out = (float*)d_out;
    int NP = N + 16;  // padded slice stride (row N = zero pad row)

    char* w = (char*)d_ws;
    size_t o = 0;
    auto alloc = [&](size_t bytes) { char* p = w + o; o += (bytes + 511) & ~511ull; return p; };
    unsigned short* h = (unsigned short*)alloc((size_t)NP * 128 * 2);   // bf16 slice-major GEMM out / agg in
    unsigned short* h2 = (unsigned short*)alloc((size_t)NP * 128 * 2);  // bf16 slice-major agg out / GEMM in
    int* rowptr = (int*)alloc(((size_t)N + 1) * 4);
    int* ssrc = (int*)alloc(((size_t)E + 256) * 4);  // +256 zero pad: branch-free batch overruns
    uint4* Wp = (uint4*)alloc(3 * 2048 * 16);
    float* stats = (float*)alloc(512 * 4);
    float* ss = (float*)alloc(512 * 4);

    int NB = (N + 1023) >> 10;  // buckets of 1024 nodes (98 for N=100000, must be <=128)
    int* ghist = (int*)alloc((size_t)NB * 16 * 4);  // line-padded counters
    int* snext = (int*)alloc((size_t)NB * 16 * 4);  // line-padded counters
    int* sbase = (int*)alloc((size_t)NB * 4);
    int* csrB = (int*)alloc(((size_t)NB + 1) * 4);
    // staging buffer aliases h2: only live during CSR build, which completes
    // (stream-ordered) before aggs_k first writes h2. Needs E + NB*16 ints << 25.6MB.
    int* staged = (int*)h2;

    prepw_k<<<24, 256, 0, stream>>>(Ws, Wp, ghist, snext, stats, ssrc + E, h, NB * 16, N, NP);
    hist_k<<<256, 256, 0, stream>>>(dst, E, ghist, NB);
    pscan_k<<<1, 128, 0, stream>>>(ghist, NB, sbase, csrB, rowptr, N, E);
    bin_k<<<(E + CHUNK - 1) / CHUNK, 256, 0, stream>>>(src, dst, E, sbase, snext, staged, NB);
    csr_k<<<NB, 1024, 0, stream>>>(staged, ghist, sbase, csrB, rowptr, ssrc, N);

    const int AGG_BLOCKS = 2048;  // multiple of 8; slice = blockIdx & 7
    const int GEMM_BLOCKS = 512;

    mgemm_k<0><<<GEMM_BLOCKS, 256, 0, stream>>>(x, nullptr, Wp, h, nullptr, N, NP);
    aggs_k<0><<<AGG_BLOCKS, 256, 0, stream>>>(h, rowptr, ssrc, (unsigned*)h2, nullptr, stats, N, NP);
    bnfin_k<<<1, 128, 0, stream>>>(stats, gammas, betas, ss, N);
    mgemm_k<1><<<GEMM_BLOCKS, 256, 0, stream>>>(nullptr, h2, Wp + 2048, h, ss, N, NP);
    aggs_k<0><<<AGG_BLOCKS, 256, 0, stream>>>(h, rowptr, ssrc, (unsigned*)h2, nullptr, stats + 256, N, NP);
    bnfin_k<<<1, 128, 0, stream>>>(stats + 256, gammas + 128, betas + 128, ss + 256, N);
    mgemm_k<1><<<GEMM_BLOCKS, 256, 0, stream>>>(nullptr, h2, Wp + 4096, h, ss + 256, N, NP);
    aggs_k<1><<<AGG_BLOCKS, 256, 0, stream>>>(h, rowptr, ssrc, nullptr, out, nullptr, N, NP);
    lsm_k<<<2048, 256, 0, stream>>>(out, N);
}

// Round 11
// 479.768 us; speedup vs baseline: 1.4922x; 1.4922x over previous
//
#include <hip/hip_runtime.h>

#define BN_EPS 1e-5f

typedef __attribute__((ext_vector_type(8))) short bf16x8;
typedef __attribute__((ext_vector_type(4))) float f32x4;

union VU {
    uint4 u;
    bf16x8 b;
};

// ---------------- CSR build: LDS multi-split bucket sort ----------------
// Bucket b = dst >> 10 (1024 nodes/bucket, NB = ceil(N/1024) <= 128).
// bin_k: per-block LDS histogram assigns local ranks (LDS atomics), ONE global
// atomic per (block,bucket) reserves a run -> 77K global atomics on line-padded
// counters instead of 1.6M on 49 shared lines (the round-1 510us serialization).

__global__ __launch_bounds__(256) void hist_k(const int* __restrict__ dst, int E,
                                              int* __restrict__ ghist, int NB) {
    __shared__ int lh[128];
    if (threadIdx.x < 128) lh[threadIdx.x] = 0;
    __syncthreads();
    for (int i = blockIdx.x * 256 + threadIdx.x; i < E; i += gridDim.x * 256)
        atomicAdd(&lh[dst[i] >> 10], 1);
    __syncthreads();
    if (threadIdx.x < 128 && threadIdx.x < NB && lh[threadIdx.x])
        atomicAdd(&ghist[threadIdx.x * 16], lh[threadIdx.x]);
}

// One-block scan over NB bucket counts (NB <= 128).
__global__ __launch_bounds__(128) void pscan_k(const int* __restrict__ ghist, int NB,
                                               int* __restrict__ sbase, int* __restrict__ csrB,
                                               int* __restrict__ rowptr, int n, int E) {
    __shared__ int pa[128], pc[128];
    int t = threadIdx.x;
    int v = (t < NB) ? ghist[t * 16] : 0;
    int vp = (v + 15) & ~15;
    pa[t] = vp;
    pc[t] = v;
    __syncthreads();
    for (int s = 1; s < 128; s <<= 1) {
        int ta = (t >= s) ? pa[t - s] : 0;
        int tc = (t >= s) ? pc[t - s] : 0;
        __syncthreads();
        pa[t] += ta;
        pc[t] += tc;
        __syncthreads();
    }
    if (t < NB) {
        sbase[t] = pa[t] - vp;
        csrB[t] = pc[t] - v;
        if (t == NB - 1) {
            csrB[NB] = pc[t];
            rowptr[n] = E;
        }
    }
}

// LDS multi-split: 2048-edge chunk per block; local ranks via LDS atomics,
// one global atomic per bucket per block, then scatter packed (src | dstLocal<<17).
#define CHUNK 2048
__global__ __launch_bounds__(256) void bin_k(const int* __restrict__ src, const int* __restrict__ dst, int E,
                                             const int* __restrict__ sbase, int* __restrict__ snext,
                                             int* __restrict__ staged, int NB) {
    __shared__ int hist[128];
    __shared__ int base[128];
    int t = threadIdx.x;
    int c0 = blockIdx.x * CHUNK;
    if (c0 >= E) return;
    if (t < 128) hist[t] = 0;
    __syncthreads();
    int bk[8], pk[8], rk[8];
#pragma unroll
    for (int k = 0; k < 8; ++k) {
        int i = c0 + k * 256 + t;
        bk[k] = -1;
        if (i < E) {
            int d = dst[i];
            int b = d >> 10;
            bk[k] = b;
            pk[k] = src[i] | ((d & 1023) << 17);
            rk[k] = atomicAdd(&hist[b], 1);
        }
    }
    __syncthreads();
    if (t < NB) base[t] = sbase[t] + atomicAdd(&snext[t * 16], hist[t]);
    __syncthreads();
#pragma unroll
    for (int k = 0; k < 8; ++k)
        if (bk[k] >= 0) staged[base[bk[k]] + rk[k]] = pk[k];
}

// One block per bucket: LDS count + scan over 1024 local nodes, write rowptr,
// then scatter ssrc within the bucket's contiguous (~64KB) CSR region.
__global__ __launch_bounds__(1024) void csr_k(const int* __restrict__ staged, const int* __restrict__ ghist,
                                              const int* __restrict__ sbase, const int* __restrict__ csrB,
                                              int* __restrict__ rowptr, int* __restrict__ ssrc, int n) {
    __shared__ int hist[1024], cur[1024];
    int b = blockIdx.x, t = threadIdx.x;
    int nodeBase = b << 10;
    hist[t] = 0;
    __syncthreads();
    int s0 = sbase[b], c = ghist[b * 16];
    for (int j = t; j < c; j += 1024) atomicAdd(&hist[staged[s0 + j] >> 17], 1);
    __syncthreads();
    int v = hist[t];
    for (int s = 1; s < 1024; s <<= 1) {
        int tv = (t >= s) ? hist[t - s] : 0;
        __syncthreads();
        hist[t] += tv;
        __syncthreads();
    }
    int ex = hist[t] - v;
    int cb = csrB[b];
    if (nodeBase + t < n) rowptr[nodeBase + t] = cb + ex;
    cur[t] = ex;
    __syncthreads();
    for (int j = t; j < c; j += 1024) {
        int e = staged[s0 + j];
        int p = atomicAdd(&cur[e >> 17], 1);
        ssrc[cb + p] = e & 131071;
    }
}

// ---------------- helpers ----------------

static __device__ __forceinline__ unsigned short f2bf(float f) {
    unsigned u = __float_as_uint(f);
    unsigned r = (u + 0x7FFFu + ((u >> 16) & 1u)) >> 16;  // RNE
    return (unsigned short)r;
}
static __device__ __forceinline__ float bf_lo(unsigned u) { return __uint_as_float(u << 16); }
static __device__ __forceinline__ float bf_hi(unsigned u) { return __uint_as_float(u & 0xFFFF0000u); }

// ---------------- prep: pack W into bf16 MFMA fragments + fold zero-inits ----------------
// Also zeroes the H pad row (slice stride n+16, row n of each slice): masked
// aggregation slots gather this zero row -> no sc-predicate in the hot loop.

__global__ __launch_bounds__(256) void prepw_k(const float* __restrict__ Ws, uint4* __restrict__ Wp,
                                               int* __restrict__ ghist, int* __restrict__ snext,
                                               float* __restrict__ stats, int* __restrict__ ssrcPad,
                                               unsigned short* __restrict__ h, int NB16, int n, int np) {
    int id = blockIdx.x * 256 + threadIdx.x;
    // folded zero-inits (replaces hipMemsetAsync launches)
    if (id < NB16) ghist[id] = 0;
    else if (id < 2 * NB16) snext[id - NB16] = 0;
    else if (id < 2 * NB16 + 512) stats[id - 2 * NB16] = 0.f;
    else if (id < 2 * NB16 + 512 + 256) ssrcPad[id - 2 * NB16 - 512] = 0;
    if (id >= 4096 && id < 4096 + 128) {
        int sl = (id - 4096) >> 4, ft = (id - 4096) & 15;
        h[((size_t)sl * np + n) * 16 + ft] = 0;  // zero pad row of each slice
    }
    if (id >= 3 * 4 * 8 * 64) return;
    int lane = id & 63;
    int nt = (id >> 6) & 7;
    int kt = (id >> 9) & 3;
    int L = id >> 11;
    int quad = lane >> 4, l16 = lane & 15;
    const float* wsrc = Ws + L * 16384 + (kt * 32 + quad * 8) * 128 + nt * 16 + l16;
    unsigned short s[8];
#pragma unroll
    for (int j = 0; j < 8; ++j) s[j] = f2bf(wsrc[j * 128]);
    uint4 pk;
    pk.x = (unsigned)s[0] | ((unsigned)s[1] << 16);
    pk.y = (unsigned)s[2] | ((unsigned)s[3] << 16);
    pk.z = (unsigned)s[4] | ((unsigned)s[5] << 16);
    pk.w = (unsigned)s[6] | ((unsigned)s[7] << 16);
    Wp[id] = pk;
}

// ---------------- MFMA GEMM: H(bf16, SLICE-MAJOR, stride np=n+16) = f(X) @ Wp ----------------
// Slice-major: slice s at H + s*np*16, rows 0..n-1 computed, row n = zero pad.
// MODE 0: X = f32 row-major (cvt fused).  MODE 1: X = bf16 slice-major, f = BN+ReLU (fused).

template <int MODE>
__global__ __launch_bounds__(256) void mgemm_k(const float* __restrict__ Xf, const unsigned short* __restrict__ Xb,
                                               const uint4* __restrict__ Wp, unsigned short* __restrict__ H,
                                               const float* __restrict__ ss, int n, int np) {
    int lane = threadIdx.x & 63;
    int quad = lane >> 4, l16 = lane & 15;
    int wid = (blockIdx.x * 256 + threadIdx.x) >> 6;
    int nw = (gridDim.x * 256) >> 6;
    int ntiles = (n + 15) >> 4;

    VU b[4][8];
#pragma unroll
    for (int kt = 0; kt < 4; ++kt)
#pragma unroll
        for (int nt = 0; nt < 8; ++nt) b[kt][nt].u = Wp[(kt * 8 + nt) * 64 + lane];

    auto loadA = [&](int tile, VU* a) {
        int row = tile * 16 + l16;
#pragma unroll
        for (int kt = 0; kt < 4; ++kt) {
            float f[8];
            if (MODE == 0) {
                const float* xr = Xf + (size_t)row * 128 + kt * 32 + quad * 8;
                float4 u0 = *(const float4*)(xr);
                float4 u1 = *(const float4*)(xr + 4);
                f[0] = u0.x; f[1] = u0.y; f[2] = u0.z; f[3] = u0.w;
                f[4] = u1.x; f[5] = u1.y; f[6] = u1.z; f[7] = u1.w;
            } else {
                int sl = kt * 2 + (quad >> 1);
                uint4 u = *(const uint4*)(Xb + ((size_t)sl * np + row) * 16 + (quad & 1) * 8);
                f[0] = bf_lo(u.x); f[1] = bf_hi(u.x); f[2] = bf_lo(u.y); f[3] = bf_hi(u.y);
                f[4] = bf_lo(u.z); f[5] = bf_hi(u.z); f[6] = bf_lo(u.w); f[7] = bf_hi(u.w);
                const float4* scp = (const float4*)(ss + kt * 32 + quad * 8);
                const float4* shp = (const float4*)(ss + 128 + kt * 32 + quad * 8);
                float4 c0 = scp[0], c1 = scp[1], d0 = shp[0], d1 = shp[1];
                f[0] = fmaxf(fmaf(f[0], c0.x, d0.x), 0.f);
                f[1] = fmaxf(fmaf(f[1], c0.y, d0.y), 0.f);
                f[2] = fmaxf(fmaf(f[2], c0.z, d0.z), 0.f);
                f[3] = fmaxf(fmaf(f[3], c0.w, d0.w), 0.f);
                f[4] = fmaxf(fmaf(f[4], c1.x, d1.x), 0.f);
                f[5] = fmaxf(fmaf(f[5], c1.y, d1.y), 0.f);
                f[6] = fmaxf(fmaf(f[6], c1.z, d1.z), 0.f);
                f[7] = fmaxf(fmaf(f[7], c1.w, d1.w), 0.f);
            }
            uint4 pk;
            pk.x = (unsigned)f2bf(f[0]) | ((unsigned)f2bf(f[1]) << 16);
            pk.y = (unsigned)f2bf(f[2]) | ((unsigned)f2bf(f[3]) << 16);
            pk.z = (unsigned)f2bf(f[4]) | ((unsigned)f2bf(f[5]) << 16);
            pk.w = (unsigned)f2bf(f[6]) | ((unsigned)f2bf(f[7]) << 16);
            a[kt].u = pk;
        }
    };

    int t = wid;
    VU a[4];
    if (t < ntiles) loadA(t, a);

    while (t < ntiles) {
        int tn = t + nw;
        VU an[4];
        if (tn < ntiles) loadA(tn, an);

        f32x4 acc[8];
#pragma unroll
        for (int nt = 0; nt < 8; ++nt) acc[nt] = (f32x4){0.f, 0.f, 0.f, 0.f};
#pragma unroll
        for (int kt = 0; kt < 4; ++kt)
#pragma unroll
            for (int nt = 0; nt < 8; ++nt)
                acc[nt] = __builtin_amdgcn_mfma_f32_16x16x32_bf16(b[kt][nt].b, a[kt].b, acc[nt], 0, 0, 0);

        int row = t * 16 + l16;
#pragma unroll
        for (int nt = 0; nt < 8; ++nt) {
            uint2 pk;
            pk.x = (unsigned)f2bf(acc[nt][0]) | ((unsigned)f2bf(acc[nt][1]) << 16);
            pk.y = (unsigned)f2bf(acc[nt][2]) | ((unsigned)f2bf(acc[nt][3]) << 16);
            *(uint2*)(H + ((size_t)nt * np + row) * 16 + quad * 4) = pk;
        }

#pragma unroll
        for (int kt = 0; kt < 4; ++kt) a[kt] = an[kt];
        t = tn;
    }
}

// ---------------- Sliced aggregation, 8 nodes per wave (round-8 structure, FINAL) ----------
// slice = blockIdx & 7 (XCD-pinned, L2-resident 3.2 MB slice). SEQUENTIAL node
// order (rounds 4/7: reorders cost more in fetch locality than they save).
// Counted loop (wave-max degree, no ballot -> cross-iteration pipelining) with
// masked slots redirected to the zero pad row (index n) -> unconditional adds.
// Plain cached loads (round 10: non-temporal hints broke the L1/L2 absorption
// of the 8-way-redundant idx loads, doubling latency).

template <int MODE>
__global__ __launch_bounds__(256) void aggs_k(const unsigned short* __restrict__ H, const int* __restrict__ rowptr,
                                              const int* __restrict__ ssrc, unsigned* __restrict__ outb,
                                              float* __restrict__ outf, float* __restrict__ stats, int n, int np) {
    __shared__ float sred[4][4][8];
    int slice = blockIdx.x & 7;
    int bg = blockIdx.x >> 3;
    int lane = threadIdx.x & 63;
    int wv = threadIdx.x >> 6;
    int g = lane >> 3;  // node group
    int f = lane & 7;   // feature pair: feats 2f, 2f+1 of this slice
    int wid = bg * 4 + wv;
    int nwave = (gridDim.x >> 3) * 4;
    const unsigned short* hs = H + (size_t)slice * np * 16 + f * 2;
    float s0 = 0, s1 = 0, q0 = 0, q1 = 0;

    for (int base = wid * 8; base < n; base += nwave * 8) {
        int node = base + g;
        bool valid = node < n;
        int cn = valid ? node : (n - 1);
        int beg = rowptr[cn];
        int end = valid ? rowptr[cn + 1] : beg;
        float ax = 0.f, ay = 0.f;

        int md = end - beg;
        md = max(md, __shfl_xor(md, 8));
        md = max(md, __shfl_xor(md, 16));
        md = max(md, __shfl_xor(md, 32));
        int nb = (md + 7) >> 3;

        int idx[8];
#pragma unroll
        for (int k = 0; k < 8; ++k) {
            int j = beg + k;
            idx[k] = (j < end) ? ssrc[j] : n;  // pad row (zeros); ssrc tail-padded
        }

        int j0 = beg;
        for (int it = 0; it < nb; ++it) {
            unsigned v[8];
#pragma unroll
            for (int k = 0; k < 8; ++k) v[k] = *(const unsigned*)(hs + (size_t)(unsigned)idx[k] * 16);
            int idn[8];
#pragma unroll
            for (int k = 0; k < 8; ++k) {
                int j = j0 + 8 + k;
                idn[k] = (j < end) ? ssrc[j] : n;  // prefetch next batch
            }
#pragma unroll
            for (int k = 0; k < 8; ++k) {
                ax += bf_lo(v[k]);
                ay += bf_hi(v[k]);
            }
#pragma unroll
            for (int k = 0; k < 8; ++k) idx[k] = idn[k];
            j0 += 8;
        }

        if (MODE == 0) {
            if (valid) outb[((size_t)slice * np + node) * 8 + f] = (unsigned)f2bf(ax) | ((unsigned)f2bf(ay) << 16);
            s0 += ax; q0 += ax * ax;
            s1 += ay; q1 += ay * ay;
        } else {
            if (valid) *(float2*)(outf + (size_t)node * 128 + slice * 16 + f * 2) = make_float2(ax, ay);
        }
    }

    if (MODE == 0) {
        // combine the 8 node-groups (lane bits 3,4,5), then cross-wave via LDS
        s0 += __shfl_xor(s0, 8); s0 += __shfl_xor(s0, 16); s0 += __shfl_xor(s0, 32);
        s1 += __shfl_xor(s1, 8); s1 += __shfl_xor(s1, 16); s1 += __shfl_xor(s1, 32);
        q0 += __shfl_xor(q0, 8); q0 += __shfl_xor(q0, 16); q0 += __shfl_xor(q0, 32);
        q1 += __shfl_xor(q1, 8); q1 += __shfl_xor(q1, 16); q1 += __shfl_xor(q1, 32);
        if (g == 0) {
            sred[wv][0][f] = s0;
            sred[wv][1][f] = s1;
            sred[wv][2][f] = q0;
            sred[wv][3][f] = q1;
        }
        __syncthreads();
        if (wv == 0 && g == 0) {
            float t0 = (sred[0][0][f] + sred[1][0][f]) + (sred[2][0][f] + sred[3][0][f]);
            float t1 = (sred[0][1][f] + sred[1][1][f]) + (sred[2][1][f] + sred[3][1][f]);
            float t2 = (sred[0][2][f] + sred[1][2][f]) + (sred[2][2][f] + sred[3][2][f]);
            float t3 = (sred[0][3][f] + sred[1][3][f]) + (sred[2][3][f] + sred[3][3][f]);
            atomicAdd(&stats[slice * 16 + 2 * f], t0);
            atomicAdd(&stats[slice * 16 + 2 * f + 1], t1);
            atomicAdd(&stats[128 + slice * 16 + 2 * f], t2);
            atomicAdd(&stats[128 + slice * 16 + 2 * f + 1], t3);
        }
    }
}

// ---------------- log_softmax in-place over out [n][128] ----------------

__global__ __launch_bounds__(256) void lsm_k(float* __restrict__ out, int n) {
    int lane = threadIdx.x & 63;
    int wid = (blockIdx.x * 256 + threadIdx.x) >> 6;
    int nw = (gridDim.x * 256) >> 6;
    for (int node = wid; node < n; node += nw) {
        float2 v = *(float2*)(out + (size_t)node * 128 + 2 * lane);
        float m = fmaxf(v.x, v.y);
#pragma unroll
        for (int off = 32; off > 0; off >>= 1) m = fmaxf(m, __shfl_xor(m, off));
        float ex = expf(v.x - m) + expf(v.y - m);
#pragma unroll
        for (int off = 32; off > 0; off >>= 1) ex += __shfl_xor(ex, off);
        float lse = m + logf(ex);
        *(float2*)(out + (size_t)node * 128 + 2 * lane) = make_float2(v.x - lse, v.y - lse);
    }
}

// ---------------- BN finalize ----------------

__global__ void bnfin_k(const float* __restrict__ stats, const float* __restrict__ gamma,
                        const float* __restrict__ beta, float* __restrict__ ss, int n) {
    int f = threadIdx.x;
    if (f < 128) {
        float mu = stats[f] / n;
        float var = stats[128 + f] / n - mu * mu;
        float rs = rsqrtf(fmaxf(var, 0.f) + BN_EPS);
        float sc = gamma[f] * rs;
        ss[f] = sc;
        ss[128 + f] = beta[f] - mu * sc;
    }
}

// ---------------- driver ----------------

extern "C" void kernel_launch(void* const* d_in, const int* in_sizes, int n_in,
                              void* d_out, int out_size, void* d_ws, size_t ws_size,
                              hipStream_t stream) {
    const float* x = (const float*)d_in[0];
    const int* ei = (const int*)d_in[1];
    const float* Ws = (const float*)d_in[2];
    const float* gammas = (const float*)d_in[3];
    const float* betas = (const float*)d_in[4];
    int N = in_sizes[0] / 128;
    int E = in_sizes[1] / 2;
    const int* src = ei;
    const int* dst = ei + E;
    float* out = (float*)d_out;
    int NP = N + 16;  // padded slice stride (row N = zero pad row)

    char* w = (char*)d_ws;
    size_t o = 0;
    auto alloc = [&](size_t bytes) { char* p = w + o; o += (bytes + 511) & ~511ull; return p; };
    unsigned short* h = (unsigned short*)alloc((size_t)NP * 128 * 2);   // bf16 slice-major GEMM out / agg in
    unsigned short* h2 = (unsigned short*)alloc((size_t)NP * 128 * 2);  // bf16 slice-major agg out / GEMM in
    int* rowptr = (int*)alloc(((size_t)N + 1) * 4);
    int* ssrc = (int*)alloc(((size_t)E + 256) * 4);  // +256 zero pad: branch-free batch overruns
    uint4* Wp = (uint4*)alloc(3 * 2048 * 16);
    float* stats = (float*)alloc(512 * 4);
    float* ss = (float*)alloc(512 * 4);

    int NB = (N + 1023) >> 10;  // buckets of 1024 nodes (98 for N=100000, must be <=128)
    int* ghist = (int*)alloc((size_t)NB * 16 * 4);  // line-padded counters
    int* snext = (int*)alloc((size_t)NB * 16 * 4);  // line-padded counters
    int* sbase = (int*)alloc((size_t)NB * 4);
    int* csrB = (int*)alloc(((size_t)NB + 1) * 4);
    // staging buffer aliases h2: only live during CSR build, which completes
    // (stream-ordered) before aggs_k first writes h2. Needs E + NB*16 ints << 25.6MB.
    int* staged = (int*)h2;

    prepw_k<<<24, 256, 0, stream>>>(Ws, Wp, ghist, snext, stats, ssrc + E, h, NB * 16, N, NP);
    hist_k<<<256, 256, 0, stream>>>(dst, E, ghist, NB);
    pscan_k<<<1, 128, 0, stream>>>(ghist, NB, sbase, csrB, rowptr, N, E);
    bin_k<<<(E + CHUNK - 1) / CHUNK, 256, 0, stream>>>(src, dst, E, sbase, snext, staged, NB);
    csr_k<<<NB, 1024, 0, stream>>>(staged, ghist, sbase, csrB, rowptr, ssrc, N);

    const int AGG_BLOCKS = 2048;  // multiple of 8; slice = blockIdx & 7
    const int GEMM_BLOCKS = 512;

    mgemm_k<0><<<GEMM_BLOCKS, 256, 0, stream>>>(x, nullptr, Wp, h, nullptr, N, NP);
    aggs_k<0><<<AGG_BLOCKS, 256, 0, stream>>>(h, rowptr, ssrc, (unsigned*)h2, nullptr, stats, N, NP);
    bnfin_k<<<1, 128, 0, stream>>>(stats, gammas, betas, ss, N);
    mgemm_k<1><<<GEMM_BLOCKS, 256, 0, stream>>>(nullptr, h2, Wp + 2048, h, ss, N, NP);
    aggs_k<0><<<AGG_BLOCKS, 256, 0, stream>>>(h, rowptr, ssrc, (unsigned*)h2, nullptr, stats + 256, N, NP);
    bnfin_k<<<1, 128, 0, stream>>>(stats + 256, gammas + 128, betas + 128, ss + 256, N);
    mgemm_k<1><<<GEMM_BLOCKS, 256, 0, stream>>>(nullptr, h2, Wp + 4096, h, ss + 256, N, NP);
    aggs_k<1><<<AGG_BLOCKS, 256, 0, stream>>>(h, rowptr, ssrc, nullptr, out, nullptr, N, NP);
    lsm_k<<<2048, 256, 0, stream>>>(out, N);
}